// Round 5
// baseline (568.895 us; speedup 1.0000x reference)
//
#include <hip/hip_runtime.h>
#include <cmath>

#define N_TOK 8192
#define C_DIM 768
#define H_DIM 3072
#define NEXP  8
#define PADCAP 18432      // 2*N_TOK + NEXP*256 (expert segments padded to 256)

typedef short short8 __attribute__((ext_vector_type(8)));
typedef unsigned short ushort8 __attribute__((ext_vector_type(8)));
typedef float f32x4  __attribute__((ext_vector_type(4)));

// fp32 -> bf16 round-to-nearest-even (finite inputs only)
__device__ __forceinline__ unsigned short f2b(float f) {
  unsigned int u = __float_as_uint(f);
  u += 0x7fffu + ((u >> 16) & 1u);
  return (unsigned short)(u >> 16);
}
__device__ __forceinline__ float b2f(unsigned short u) {
  return __uint_as_float((unsigned int)u << 16);
}
__device__ __forceinline__ void gll(const char* g, char* l) {
  __builtin_amdgcn_global_load_lds((const __attribute__((address_space(1))) void*)g,
                                   (__attribute__((address_space(3))) void*)l, 16, 0, 0);
}

// ---------------- gating: fp64 scores, top-2, softmax, counts ----------------
// also zeroes this block's 64 token rows of `out` (fc2 accumulates into out
// with f32 atomics; folding the zeroing here saves a memset dispatch)
__global__ __launch_bounds__(256) void gate_kernel(
    const float* __restrict__ x, const float* __restrict__ gw,
    const float* __restrict__ gb, int* __restrict__ counts,
    int* __restrict__ tok_e, int* __restrict__ tok_r, float* __restrict__ tok_w,
    float* __restrict__ out) {
  __shared__ float gwl[NEXP * C_DIM];
  __shared__ double red[256][NEXP];
  int tid = threadIdx.x;
  float4* ob = (float4*)(out + (size_t)blockIdx.x * 64 * C_DIM);
  for (int i = tid; i < 64 * C_DIM / 4; i += 256) ob[i] = (float4){0.f, 0.f, 0.f, 0.f};
  const float4* gw4 = (const float4*)gw;
  float4* gl4 = (float4*)gwl;
  for (int i = tid; i < NEXP * C_DIM / 4; i += 256) gl4[i] = gw4[i];
  __syncthreads();
  int tl = tid & 63;   // token within block
  int kc = tid >> 6;   // k-chunk 0..3 (192 each)
  int t = blockIdx.x * 64 + tl;
  double acc[NEXP];
#pragma unroll
  for (int e = 0; e < NEXP; e++) acc[e] = 0.0;
  const float* xr = x + (size_t)t * C_DIM;
  for (int k = kc * 192; k < kc * 192 + 192; k++) {
    double xv = (double)xr[k];
#pragma unroll
    for (int e = 0; e < NEXP; e++) acc[e] += xv * (double)gwl[e * C_DIM + k];
  }
#pragma unroll
  for (int e = 0; e < NEXP; e++) red[tid][e] = acc[e];
  __syncthreads();
  if (tid < 64) {
    double s[NEXP];
#pragma unroll
    for (int e = 0; e < NEXP; e++)
      s[e] = (double)gb[e] + red[tid][e] + red[tid + 64][e] + red[tid + 128][e] + red[tid + 192][e];
    // top-2, ties -> lower index first (matches jax.lax.top_k)
    double best = s[0], sec = -1e300; int bi = 0, si = -1;
#pragma unroll
    for (int e = 1; e < NEXP; e++) {
      if (s[e] > best)      { sec = best; si = bi; best = s[e]; bi = e; }
      else if (s[e] > sec)  { sec = s[e]; si = e; }
    }
    double ex = exp(sec - best);
    double den = 1.0 + ex;
    tok_e[2 * t] = bi;  tok_e[2 * t + 1] = si;
    tok_w[2 * t] = (float)(1.0 / den);  tok_w[2 * t + 1] = (float)(ex / den);
    tok_r[2 * t]     = atomicAdd(&counts[bi], 1);
    tok_r[2 * t + 1] = atomicAdd(&counts[si], 1);
  }
}

// ---------------- padded offsets (segments rounded up to 256 rows) ----------
__global__ void offsets_kernel(const int* __restrict__ counts, int* __restrict__ po) {
  if (threadIdx.x == 0 && blockIdx.x == 0) {
    int s = 0;
    for (int e = 0; e < NEXP; e++) { po[e] = s; s += (counts[e] + 255) & ~255; }
    po[NEXP] = s;
  }
}

// -------- scatter token ids + gate weights into permuted order --------------
__global__ __launch_bounds__(256) void scatter_kernel(
    const int* __restrict__ tok_e, const int* __restrict__ tok_r,
    const float* __restrict__ tok_w, const int* __restrict__ po,
    int* __restrict__ perm_t, float* __restrict__ perm_w) {
  int t = blockIdx.x * 256 + threadIdx.x;
#pragma unroll
  for (int k = 0; k < 2; k++) {
    int e = tok_e[2 * t + k];
    int pos = po[e] + tok_r[2 * t + k];
    perm_t[pos] = t;
    perm_w[pos] = tok_w[2 * t + k];
  }
}

// ---------------- gather x rows into permuted bf16 matrix -------------------
__global__ __launch_bounds__(256) void gather_kernel(
    const float* __restrict__ x, const int* __restrict__ po,
    const int* __restrict__ perm_t, unsigned short* __restrict__ xg) {
  int row = blockIdx.x * 4 + (threadIdx.x >> 6);
  if (row >= po[NEXP]) return;
  int l = threadIdx.x & 63;
  int t = perm_t[row];           // pad rows: perm_t zeroed -> t=0 (safe, wgt=0)
  const float4* src = (const float4*)(x + (size_t)t * C_DIM);
  ushort4* dst = (ushort4*)(xg + (size_t)row * C_DIM);
#pragma unroll
  for (int j = 0; j < 3; j++) {
    float4 v = src[l + j * 64];
    ushort4 o; o.x = f2b(v.x); o.y = f2b(v.y); o.z = f2b(v.z); o.w = f2b(v.w);
    dst[l + j * 64] = o;
  }
}

// ---------------- fp32 -> bf16 weight conversion (one matrix set) -----------
__global__ __launch_bounds__(256) void wconv_kernel(
    const float* __restrict__ src, unsigned short* __restrict__ dst, int n4) {
  int stride = gridDim.x * blockDim.x;
  for (int i = blockIdx.x * blockDim.x + threadIdx.x; i < n4; i += stride) {
    float4 v = ((const float4*)src)[i];
    ushort4 o; o.x = f2b(v.x); o.y = f2b(v.y); o.z = f2b(v.z); o.w = f2b(v.w);
    ((ushort4*)dst)[i] = o;
  }
}

// ---------- 512-thread 128x128 tile, BK=64, LDS double-buffer (FC1) ---------
// r1-proven structure: 2 blocks/CU so co-resident blocks fill barrier
// bubbles -- tolerates fc1's short K (768 = 12 K-tiles) where the deep
// 8-phase pipeline cannot amortize its fill/drain (r3: 596 TF vs this 725).
__device__ __forceinline__ void gemm_core512(
    const unsigned short* A, int lda, const unsigned short* B, int ldb, int K,
    char* lds, int tid, f32x4 acc[4][2]) {
  const int w = tid >> 6, l = tid & 63;
  const int wr = w >> 2, wc = w & 3;
  const int rowa = wr * 64 + (l & 15);
  const int rowb = wc * 32 + (l & 15);
  const int kc = l >> 4;
  const int sa0 = (kc ^ ((rowa >> 1) & 7)) * 16;
  const int sb0 = (kc ^ ((rowb >> 1) & 7)) * 16;
  const int r0 = tid >> 3,          cg0 = (tid & 7) ^ ((r0 >> 1) & 7);
  const int r1 = (512 + tid) >> 3,  cg1 = ((512 + tid) & 7) ^ ((r1 >> 1) & 7);
  const char* gA0 = (const char*)(A + (size_t)r0 * lda) + cg0 * 16;
  const char* gA1 = (const char*)(A + (size_t)r1 * lda) + cg1 * 16;
  const char* gB0 = (const char*)(B + (size_t)r0 * ldb) + cg0 * 16;
  const char* gB1 = (const char*)(B + (size_t)r1 * ldb) + cg1 * 16;
  const int wb = w * 1024;           // wave-uniform LDS base (+ lane*16 by HW)
  const int iters = K >> 6;
  gll(gA0, lds + wb);
  gll(gA1, lds + 8192 + wb);
  gll(gB0, lds + 16384 + wb);
  gll(gB1, lds + 24576 + wb);
#pragma unroll 1
  for (int kt = 0; kt < iters; kt++) {
    __syncthreads();                       // publishes buf kt&1
    if (kt + 1 < iters) {                  // prefetch tile kt+1 -> other buf
      size_t kb = (size_t)(kt + 1) * 128;  // 64 elems * 2B
      char* nb = lds + ((kt + 1) & 1) * 32768;
      gll(gA0 + kb, nb + wb);
      gll(gA1 + kb, nb + 8192 + wb);
      gll(gB0 + kb, nb + 16384 + wb);
      gll(gB1 + kb, nb + 24576 + wb);
    }
    char* bb = lds + (kt & 1) * 32768;
#pragma unroll
    for (int s = 0; s < 2; s++) {
      const int sxa = sa0 ^ (s << 6);      // chunk index ^4 == byte ^64
      const int sxb = sb0 ^ (s << 6);
      short8 af[4], bf2[2];
#pragma unroll
      for (int mi = 0; mi < 4; mi++)
        af[mi] = *(const short8*)(bb + (rowa + mi * 16) * 128 + sxa);
#pragma unroll
      for (int ni = 0; ni < 2; ni++)
        bf2[ni] = *(const short8*)(bb + 16384 + (rowb + ni * 16) * 128 + sxb);
#pragma unroll
      for (int mi = 0; mi < 4; mi++)
#pragma unroll
        for (int ni = 0; ni < 2; ni++)
          acc[mi][ni] = __builtin_amdgcn_mfma_f32_16x16x32_bf16(af[mi], bf2[ni], acc[mi][ni], 0, 0, 0);
    }
  }
}

// ---------------- FC1: h = gelu(xg @ w_fc^T + b_fc), bf16 out ---------------
// grid 3456 = 8 XCD-slots x 18 strips x 24 col-blocks; 2 blocks/CU -> 96%
// packing. Epilogue stages the 128x128 bf16 tile through LDS (stride 136)
// so global stores are contiguous 256B/row (WRITE_SIZE 196->104 MB, r4).
__global__ __launch_bounds__(512, 4) void fc1_kernel(
    const unsigned short* __restrict__ xg, const unsigned short* __restrict__ wfcb,
    const float* __restrict__ bfc, const int* __restrict__ po,
    unsigned short* __restrict__ h) {
  __shared__ char lds[65536];
  int bid = blockIdx.x;
  int r8 = bid & 7, g8 = bid >> 3;     // g8: 0..431
  int col = g8 % 24;
  int Sp  = g8 / 24;                   // 0..17
  int y   = r8 * 18 + Sp;              // 0..143
  int row0 = y * 128;
  if (row0 >= po[NEXP]) return;
  int e = 0;
#pragma unroll
  for (int i = 1; i < NEXP; i++) if (row0 >= po[i]) e = i;
  int n0 = col * 128;
  int tid = threadIdx.x;
  f32x4 acc[4][2];
#pragma unroll
  for (int mi = 0; mi < 4; mi++)
#pragma unroll
    for (int ni = 0; ni < 2; ni++) acc[mi][ni] = (f32x4){0.f, 0.f, 0.f, 0.f};
  gemm_core512(xg + (size_t)row0 * C_DIM, C_DIM,
               wfcb + (size_t)e * H_DIM * C_DIM + (size_t)n0 * C_DIM, C_DIM, C_DIM,
               lds, tid, acc);
  int w = tid >> 6, l = tid & 63;
  int wr = w >> 2, wc = w & 3, q = l >> 4, lr = l & 15;
  const float* bias = bfc + (size_t)e * H_DIM;
  // gelu(tanh-approx) via sigmoid: 0.5v(1+tanh(z)) = v / (1 + exp2(-2*log2e*z))
  __syncthreads();                       // all waves done reading gemm LDS
  unsigned short* lout = (unsigned short*)lds;
  const int LST = 136;                   // row stride (ushorts)
#pragma unroll
  for (int ni = 0; ni < 2; ni++) {
    int lcol = wc * 32 + ni * 16 + lr;
    float bv = bias[n0 + lcol];
#pragma unroll
    for (int mi = 0; mi < 4; mi++) {
#pragma unroll
      for (int r = 0; r < 4; r++) {
        int lrow = wr * 64 + mi * 16 + q * 4 + r;
        float v = acc[mi][ni][r] + bv;
        float z = v * fmaf(0.0356774081f, v * v, 0.7978845608f);
        float ex = __builtin_amdgcn_exp2f(-2.8853900818f * z);
        float g = v * __builtin_amdgcn_rcpf(1.0f + ex);
        lout[lrow * LST + lcol] = f2b(g);
      }
    }
  }
  __syncthreads();
  // coalesced write-out: 2048 ushort8 chunks; wave covers 4 full 256B rows
#pragma unroll
  for (int p = 0; p < 4; p++) {
    int idx = p * 512 + tid;
    int row = idx >> 4, c8 = idx & 15;
    ushort8 v = *(const ushort8*)(lout + row * LST + c8 * 8);
    *(ushort8*)(h + (size_t)(row0 + row) * H_DIM + n0 + c8 * 8) = v;
  }
}

// ================= 256x256 tile, BK=64, 8-phase deep pipeline (FC2) =========
__device__ __forceinline__ void gemm8p(
    const char* __restrict__ Ab, size_t ldaB,
    const char* __restrict__ Bb, size_t ldbB, int ktiles,
    char* lds, int tid, f32x4 acc[8][4]) {
  const int w = tid >> 6, l = tid & 63;
  const int wr = w >> 2, wc = w & 3;
  const int lr = l & 15, kc = l >> 4;
  const int sw = (lr >> 1) & 7;
  const int s0 = ((kc ^ sw) << 4);         // kk=0 slot byte
  const int s1 = s0 ^ 64;                  // kk=1: chunk+4 == slot^4
  const int arow = ((wr << 7) + lr) << 7;            // A: row*128
  const int brow = 32768 + (((wc << 6) + lr) << 7);  // B region
  const int rl0 = tid >> 3;
  const int cg0 = (tid & 7) ^ ((rl0 >> 1) & 7);
  const size_t oA0 = (size_t)rl0 * ldaB + (cg0 << 4);
  const size_t oA1 = oA0 + (ldaB << 6);
  const size_t oB0 = (size_t)rl0 * ldbB + (cg0 << 4);
  const size_t oB1 = oB0 + (ldbB << 6);
  const int wb = w << 10;                  // wave-uniform LDS base (+lane*16)

#define SA(b, h, kt) do { \
    const char* s_ = Ab + (size_t)(h) * 128 * ldaB + (size_t)(kt) * 128; \
    gll(s_ + oA0, lds + (b) * 65536 + (h) * 16384 + wb); \
    gll(s_ + oA1, lds + (b) * 65536 + (h) * 16384 + 8192 + wb); } while (0)
#define SB(b, h, kt) do { \
    const char* s_ = Bb + (size_t)(h) * 128 * ldbB + (size_t)(kt) * 128; \
    gll(s_ + oB0, lds + (b) * 65536 + 32768 + (h) * 16384 + wb); \
    gll(s_ + oB1, lds + (b) * 65536 + 32768 + (h) * 16384 + 8192 + wb); } while (0)
#define BAR() asm volatile("s_barrier" ::: "memory")
#define RDA(B, mb) do { \
    for (int mi = 0; mi < 4; mi++) { \
      af[mi][0] = *(const short8*)(lds + (B) + arow + ((mb) + mi) * 2048 + s0); \
      af[mi][1] = *(const short8*)(lds + (B) + arow + ((mb) + mi) * 2048 + s1); } } while (0)
#define RDB(B, nb) do { \
    for (int ni = 0; ni < 2; ni++) { \
      bf[(nb) + ni][0] = *(const short8*)(lds + (B) + brow + ((nb) + ni) * 2048 + s0); \
      bf[(nb) + ni][1] = *(const short8*)(lds + (B) + brow + ((nb) + ni) * 2048 + s1); } } while (0)
#define MM(mb, nb) do { \
    __builtin_amdgcn_s_setprio(1); \
    for (int mi = 0; mi < 4; mi++) \
      for (int ni = 0; ni < 2; ni++) \
        for (int kk = 0; kk < 2; kk++) \
          acc[(mb) + mi][(nb) + ni] = __builtin_amdgcn_mfma_f32_16x16x32_bf16( \
              af[mi][kk], bf[(nb) + ni][kk], acc[(mb) + mi][(nb) + ni], 0, 0, 0); \
    __builtin_amdgcn_s_setprio(0); } while (0)

  short8 af[4][2], bf[4][2];
  // prologue: tile0 (4 halves) then B of tile1 -> first wait retires tile0
  SB(0, 0, 0); SB(0, 1, 0); SA(0, 0, 0); SA(0, 1, 0);
  SB(1, 0, 1); SB(1, 1, 1);
  asm volatile("s_waitcnt vmcnt(4)" ::: "memory");
  BAR();
  const int iters = ktiles >> 1;
#pragma unroll 1
  for (int i = 0; i < iters; i++) {
    const int t1 = 2 * i + 1, t2 = 2 * i + 2, t3 = 2 * i + 3;
    const bool nl = (i + 1 < iters);
    // ---- K-tile 2i from buf0 ----
    RDA(0, 0); RDB(0, 0);          // p0
    SA(1, 0, t1);
    BAR(); MM(0, 0); BAR();
    RDB(0, 2);                     // p1
    SA(1, 1, t1);
    BAR(); MM(0, 2); BAR();
    RDA(0, 4);                     // p2
    if (nl) SB(0, 0, t2);
    BAR(); MM(4, 2); BAR();
    if (nl) SB(0, 1, t2);          // p3
    BAR(); MM(4, 0);
    if (nl) asm volatile("s_waitcnt vmcnt(4)" ::: "memory");
    else    asm volatile("s_waitcnt vmcnt(0)" ::: "memory");
    BAR();                         // publishes buf1 (tile 2i+1)
    // ---- K-tile 2i+1 from buf1 ----
    RDA(65536, 0); RDB(65536, 0);  // p4
    if (nl) SA(0, 0, t2);
    BAR(); MM(0, 0); BAR();
    RDB(65536, 2);                 // p5
    if (nl) SA(0, 1, t2);
    BAR(); MM(0, 2); BAR();
    RDA(65536, 4);                 // p6
    if (nl) SB(1, 0, t3);
    BAR(); MM(4, 2); BAR();
    if (nl) SB(1, 1, t3);          // p7
    BAR(); MM(4, 0);
    if (nl) {
      asm volatile("s_waitcnt vmcnt(4)" ::: "memory");
      BAR();                       // publishes buf0 (tile 2i+2)
    }
  }
#undef SA
#undef SB
#undef BAR
#undef RDA
#undef RDB
#undef MM
}

// -------- FC2: out[tok] += wgt * (h @ w_proj^T + b_proj) via f32 atomics ----
// K=3072 single pass, grid 216 = 8 x 9 x 3. Each token row receives exactly
// two atomic f32 adds (one per selected expert); f32 add of 2 operands is
// commutative-exact -> deterministic. Replaces part buffer + combine kernel.
__global__ __launch_bounds__(512, 2) void fc2_kernel(
    const unsigned short* __restrict__ h, const unsigned short* __restrict__ wpjb,
    const float* __restrict__ bproj, const int* __restrict__ po,
    const float* __restrict__ perm_w, const int* __restrict__ perm_t,
    float* __restrict__ out) {
  __shared__ char lds[131072];
  int bid = blockIdx.x;
  int r8 = bid & 7, g8 = bid >> 3;     // g8: 0..26
  int col = g8 % 3;
  int Sp  = g8 / 3;                    // 0..8
  int y   = r8 * 9 + Sp;               // 0..71
  int row0 = y * 256;
  if (row0 >= po[NEXP]) return;
  int e = 0;
#pragma unroll
  for (int i = 1; i < NEXP; i++) if (row0 >= po[i]) e = i;
  int n0 = col * 256;
  int tid = threadIdx.x;
  f32x4 acc[8][4];
#pragma unroll
  for (int mi = 0; mi < 8; mi++)
#pragma unroll
    for (int ni = 0; ni < 4; ni++) acc[mi][ni] = (f32x4){0.f, 0.f, 0.f, 0.f};
  gemm8p((const char*)(h + (size_t)row0 * H_DIM), (size_t)H_DIM * 2,
         (const char*)(wpjb + (size_t)e * C_DIM * H_DIM + (size_t)n0 * H_DIM),
         (size_t)H_DIM * 2, H_DIM / 64, lds, tid, acc);
  int w = tid >> 6, l = tid & 63;
  int wr = w >> 2, wc = w & 3, lr = l & 15, q = l >> 4;
  const float* bias = bproj + (size_t)e * C_DIM;
#pragma unroll
  for (int mi = 0; mi < 8; mi++) {
#pragma unroll
    for (int r = 0; r < 4; r++) {
      int pos = row0 + wr * 128 + mi * 16 + q * 4 + r;
      float wgt = perm_w[pos];     // 0 for pad rows (memset) -> skip
      if (wgt != 0.0f) {
        float* orow = out + (size_t)perm_t[pos] * C_DIM;
#pragma unroll
        for (int ni = 0; ni < 4; ni++) {
          int colw = n0 + wc * 64 + ni * 16 + lr;
          atomicAdd(orow + colw, (acc[mi][ni][r] + bias[colw]) * wgt);
        }
      }
    }
  }
}

extern "C" void kernel_launch(void* const* d_in, const int* in_sizes, int n_in,
                              void* d_out, int out_size, void* d_ws, size_t ws_size,
                              hipStream_t stream) {
  const float* x     = (const float*)d_in[0];
  const float* gw    = (const float*)d_in[1];
  const float* gb    = (const float*)d_in[2];
  const float* wfc   = (const float*)d_in[3];
  const float* bfc   = (const float*)d_in[4];
  const float* wproj = (const float*)d_in[5];
  const float* bproj = (const float*)d_in[6];
  float* out = (float*)d_out;
  char* ws = (char*)d_ws;

  // ws layout (~179.7 MB): wpjb overlays wfcb (dead after fc1); its wconv
  // runs after fc1.
  int*   counts  = (int*)(ws + 0);
  int*   po      = (int*)(ws + 64);
  int*   tok_e   = (int*)(ws + 256);
  int*   tok_r   = (int*)(ws + 65792);
  float* tok_w   = (float*)(ws + 131328);
  int*   perm_t  = (int*)(ws + 262400);      // 18432 ints -> 336128
  float* perm_w  = (float*)(ws + 336128);    // 18432 f32  -> 409856
  const size_t ROUT_END = 409856;
  unsigned short* wfcb = (unsigned short*)(ws + 409856);     // 8x3072x768 bf16 -> 38,158,592
  unsigned short* wpjb = (unsigned short*)(ws + 409856);     // overlay after fc1
  unsigned short* xg   = (unsigned short*)(ws + 38158592);   // 18432x768 bf16 -> 66,470,144
  unsigned short* hbuf = (unsigned short*)(ws + 66470144);   // 18432x3072 bf16 -> 179,716,352

  hipMemsetAsync(ws, 0, ROUT_END, stream);

  const int WN4 = NEXP * H_DIM * C_DIM / 4;
  gate_kernel<<<N_TOK / 64, 256, 0, stream>>>(x, gw, gb, counts, tok_e, tok_r, tok_w, out);
  offsets_kernel<<<1, 64, 0, stream>>>(counts, po);
  scatter_kernel<<<N_TOK / 256, 256, 0, stream>>>(tok_e, tok_r, tok_w, po, perm_t, perm_w);
  gather_kernel<<<PADCAP / 4, 256, 0, stream>>>(x, po, perm_t, xg);
  wconv_kernel<<<2048, 256, 0, stream>>>(wfc, wfcb, WN4);
  fc1_kernel<<<8 * 18 * 24, 512, 0, stream>>>(xg, wfcb, bfc, po, hbuf);
  wconv_kernel<<<2048, 256, 0, stream>>>(wproj, wpjb, WN4);
  fc2_kernel<<<8 * 9 * 3, 512, 0, stream>>>(hbuf, wpjb, bproj, po, perm_w, perm_t, out);
}

// Round 7
// 491.038 us; speedup vs baseline: 1.1586x; 1.1586x over previous
//
#include <hip/hip_runtime.h>
#include <cmath>

#define N_TOK 8192
#define C_DIM 768
#define H_DIM 3072
#define NEXP  8
#define PADCAP 18432      // 2*N_TOK + NEXP*256 (expert segments padded to 256)

typedef short short8 __attribute__((ext_vector_type(8)));
typedef unsigned short ushort8 __attribute__((ext_vector_type(8)));
typedef float f32x4  __attribute__((ext_vector_type(4)));

// fp32 -> bf16 round-to-nearest-even (finite inputs only)
__device__ __forceinline__ unsigned short f2b(float f) {
  unsigned int u = __float_as_uint(f);
  u += 0x7fffu + ((u >> 16) & 1u);
  return (unsigned short)(u >> 16);
}
__device__ __forceinline__ float b2f(unsigned short u) {
  return __uint_as_float((unsigned int)u << 16);
}
__device__ __forceinline__ void gll(const char* g, char* l) {
  __builtin_amdgcn_global_load_lds((const __attribute__((address_space(1))) void*)g,
                                   (__attribute__((address_space(3))) void*)l, 16, 0, 0);
}

// ============ gate + wconv(w_fc) + perm_w zero, one dispatch ================
// grid 2048 x 256. Blocks 0..127: fp64 gating (identical math to r4).
// All blocks: grid-stride w_fc fp32->bf16 and perm_w zeroing (perm_w is
// written only in the NEXT dispatch -> no ordering hazard). counts must be
// zeroed BEFORE this kernel (64B memsetAsync).
__global__ __launch_bounds__(256) void gate_wconv_kernel(
    const float* __restrict__ x, const float* __restrict__ gw,
    const float* __restrict__ gb, const float* __restrict__ wfc,
    int* __restrict__ counts, int* __restrict__ tok_e, int* __restrict__ tok_r,
    float* __restrict__ tok_w, float* __restrict__ perm_w,
    unsigned short* __restrict__ wfcb) {
  __shared__ float gwl[NEXP * C_DIM];          // 24576 B
  __shared__ double red[256][NEXP];            // 16384 B
  const int tid = threadIdx.x, bid = blockIdx.x;
  const int nthr = gridDim.x * 256;
  const int gtid = bid * 256 + tid;

  // perm_w zero (pad rows must read as weight 0 in fc2)
  for (int i = gtid; i < PADCAP; i += nthr) perm_w[i] = 0.0f;

  // wconv w_fc -> bf16
  {
    const int n4 = NEXP * H_DIM * C_DIM / 4;
    for (int i = gtid; i < n4; i += nthr) {
      float4 v = ((const float4*)wfc)[i];
      ushort4 o; o.x = f2b(v.x); o.y = f2b(v.y); o.z = f2b(v.z); o.w = f2b(v.w);
      ((ushort4*)wfcb)[i] = o;
    }
  }

  if (bid >= N_TOK / 64) return;

  // ---- gating: fp64 scores, top-2, softmax, counts (r4-identical) ----
  const float4* gw4 = (const float4*)gw;
  float4* gl4 = (float4*)gwl;
  for (int i = tid; i < NEXP * C_DIM / 4; i += 256) gl4[i] = gw4[i];
  __syncthreads();
  int tl = tid & 63;   // token within block
  int kc = tid >> 6;   // k-chunk 0..3 (192 each)
  int t = bid * 64 + tl;
  double acc[NEXP];
#pragma unroll
  for (int e = 0; e < NEXP; e++) acc[e] = 0.0;
  const float* xr = x + (size_t)t * C_DIM;
  for (int k = kc * 192; k < kc * 192 + 192; k++) {
    double xv = (double)xr[k];
#pragma unroll
    for (int e = 0; e < NEXP; e++) acc[e] += xv * (double)gwl[e * C_DIM + k];
  }
#pragma unroll
  for (int e = 0; e < NEXP; e++) red[tid][e] = acc[e];
  __syncthreads();
  if (tid < 64) {
    double s[NEXP];
#pragma unroll
    for (int e = 0; e < NEXP; e++)
      s[e] = (double)gb[e] + red[tid][e] + red[tid + 64][e] + red[tid + 128][e] + red[tid + 192][e];
    // top-2, ties -> lower index first (matches jax.lax.top_k)
    double best = s[0], sec = -1e300; int bi = 0, si = -1;
#pragma unroll
    for (int e = 1; e < NEXP; e++) {
      if (s[e] > best)      { sec = best; si = bi; best = s[e]; bi = e; }
      else if (s[e] > sec)  { sec = s[e]; si = e; }
    }
    double ex = exp(sec - best);
    double den = 1.0 + ex;
    tok_e[2 * t] = bi;  tok_e[2 * t + 1] = si;
    tok_w[2 * t] = (float)(1.0 / den);  tok_w[2 * t + 1] = (float)(ex / den);
    tok_r[2 * t]     = atomicAdd(&counts[bi], 1);
    tok_r[2 * t + 1] = atomicAdd(&counts[si], 1);
  }
}

// ========= scatgath: offsets + scatter + gather, one dispatch ===============
// counts is final (previous dispatch). Every thread recomputes the padded
// prefix po locally (8 ints, L2-hit); block 0 publishes po[] for fc1/fc2.
// Token-driven: 64-lane group j handles routing entry j (token j>>1): writes
// tok_pos/perm_w (lane 0) and copies the x row -> permuted bf16 xg.
__global__ __launch_bounds__(256) void scatgath_kernel(
    const float* __restrict__ x, const int* __restrict__ counts,
    const int* __restrict__ tok_e, const int* __restrict__ tok_r,
    const float* __restrict__ tok_w, int* __restrict__ po,
    int* __restrict__ tok_pos, float* __restrict__ perm_w,
    unsigned short* __restrict__ xg) {
  const int tid = threadIdx.x, bid = blockIdx.x;
  int pol[NEXP + 1];
  {
    int s = 0;
#pragma unroll
    for (int e = 0; e < NEXP; e++) { pol[e] = s; s += (counts[e] + 255) & ~255; }
    pol[NEXP] = s;
  }
  if (bid == 0 && tid < NEXP + 1) po[tid] = pol[tid];
  const int gtid = bid * 256 + tid;
  const int grp = gtid >> 6, l = tid & 63;
  const int ngrp = (gridDim.x * 256) >> 6;
  for (int j = grp; j < 2 * N_TOK; j += ngrp) {
    int t = j >> 1;
    int e = tok_e[j];
    int pos = pol[e] + tok_r[j];
    if (l == 0) { tok_pos[j] = pos; perm_w[pos] = tok_w[j]; }
    const float4* src = (const float4*)(x + (size_t)t * C_DIM);
    ushort4* dst = (ushort4*)(xg + (size_t)pos * C_DIM);
#pragma unroll
    for (int q = 0; q < 3; q++) {
      float4 v = src[l + q * 64];
      ushort4 o; o.x = f2b(v.x); o.y = f2b(v.y); o.z = f2b(v.z); o.w = f2b(v.w);
      dst[l + q * 64] = o;
    }
  }
}

// ---------------- fp32 -> bf16 weight conversion (w_proj, after fc1) --------
__global__ __launch_bounds__(256) void wconv_kernel(
    const float* __restrict__ src, unsigned short* __restrict__ dst, int n4) {
  int stride = gridDim.x * blockDim.x;
  for (int i = blockIdx.x * blockDim.x + threadIdx.x; i < n4; i += stride) {
    float4 v = ((const float4*)src)[i];
    ushort4 o; o.x = f2b(v.x); o.y = f2b(v.y); o.z = f2b(v.z); o.w = f2b(v.w);
    ((ushort4*)dst)[i] = o;
  }
}

// ---------- 512-thread 128x128 tile, BK=64, LDS double-buffer (FC1) ---------
__device__ __forceinline__ void gemm_core512(
    const unsigned short* A, int lda, const unsigned short* B, int ldb, int K,
    char* lds, int tid, f32x4 acc[4][2]) {
  const int w = tid >> 6, l = tid & 63;
  const int wr = w >> 2, wc = w & 3;
  const int rowa = wr * 64 + (l & 15);
  const int rowb = wc * 32 + (l & 15);
  const int kc = l >> 4;
  const int sa0 = (kc ^ ((rowa >> 1) & 7)) * 16;
  const int sb0 = (kc ^ ((rowb >> 1) & 7)) * 16;
  const int r0 = tid >> 3,          cg0 = (tid & 7) ^ ((r0 >> 1) & 7);
  const int r1 = (512 + tid) >> 3,  cg1 = ((512 + tid) & 7) ^ ((r1 >> 1) & 7);
  const char* gA0 = (const char*)(A + (size_t)r0 * lda) + cg0 * 16;
  const char* gA1 = (const char*)(A + (size_t)r1 * lda) + cg1 * 16;
  const char* gB0 = (const char*)(B + (size_t)r0 * ldb) + cg0 * 16;
  const char* gB1 = (const char*)(B + (size_t)r1 * ldb) + cg1 * 16;
  const int wb = w * 1024;           // wave-uniform LDS base (+ lane*16 by HW)
  const int iters = K >> 6;
  gll(gA0, lds + wb);
  gll(gA1, lds + 8192 + wb);
  gll(gB0, lds + 16384 + wb);
  gll(gB1, lds + 24576 + wb);
#pragma unroll 1
  for (int kt = 0; kt < iters; kt++) {
    __syncthreads();                       // publishes buf kt&1
    if (kt + 1 < iters) {                  // prefetch tile kt+1 -> other buf
      size_t kb = (size_t)(kt + 1) * 128;  // 64 elems * 2B
      char* nb = lds + ((kt + 1) & 1) * 32768;
      gll(gA0 + kb, nb + wb);
      gll(gA1 + kb, nb + 8192 + wb);
      gll(gB0 + kb, nb + 16384 + wb);
      gll(gB1 + kb, nb + 24576 + wb);
    }
    char* bb = lds + (kt & 1) * 32768;
#pragma unroll
    for (int s = 0; s < 2; s++) {
      const int sxa = sa0 ^ (s << 6);      // chunk index ^4 == byte ^64
      const int sxb = sb0 ^ (s << 6);
      short8 af[4], bf2[2];
#pragma unroll
      for (int mi = 0; mi < 4; mi++)
        af[mi] = *(const short8*)(bb + (rowa + mi * 16) * 128 + sxa);
#pragma unroll
      for (int ni = 0; ni < 2; ni++)
        bf2[ni] = *(const short8*)(bb + 16384 + (rowb + ni * 16) * 128 + sxb);
#pragma unroll
      for (int mi = 0; mi < 4; mi++)
#pragma unroll
        for (int ni = 0; ni < 2; ni++)
          acc[mi][ni] = __builtin_amdgcn_mfma_f32_16x16x32_bf16(af[mi], bf2[ni], acc[mi][ni], 0, 0, 0);
    }
  }
}

// ---------------- FC1: h = gelu(xg @ w_fc^T + b_fc), bf16 out ---------------
// grid 3456 = 8 XCD-slots x 18 strips x 24 col-blocks; 2 blocks/CU.
// LDS-staged epilogue -> contiguous 256B-row stores (WRITE 196->104 MB, r4).
__global__ __launch_bounds__(512, 4) void fc1_kernel(
    const unsigned short* __restrict__ xg, const unsigned short* __restrict__ wfcb,
    const float* __restrict__ bfc, const int* __restrict__ po,
    unsigned short* __restrict__ h) {
  __shared__ char lds[65536];
  int bid = blockIdx.x;
  int r8 = bid & 7, g8 = bid >> 3;     // g8: 0..431
  int col = g8 % 24;
  int Sp  = g8 / 24;                   // 0..17
  int y   = r8 * 18 + Sp;              // 0..143
  int row0 = y * 128;
  if (row0 >= po[NEXP]) return;
  int e = 0;
#pragma unroll
  for (int i = 1; i < NEXP; i++) if (row0 >= po[i]) e = i;
  int n0 = col * 128;
  int tid = threadIdx.x;
  f32x4 acc[4][2];
#pragma unroll
  for (int mi = 0; mi < 4; mi++)
#pragma unroll
    for (int ni = 0; ni < 2; ni++) acc[mi][ni] = (f32x4){0.f, 0.f, 0.f, 0.f};
  gemm_core512(xg + (size_t)row0 * C_DIM, C_DIM,
               wfcb + (size_t)e * H_DIM * C_DIM + (size_t)n0 * C_DIM, C_DIM, C_DIM,
               lds, tid, acc);
  int w = tid >> 6, l = tid & 63;
  int wr = w >> 2, wc = w & 3, q = l >> 4, lr = l & 15;
  const float* bias = bfc + (size_t)e * H_DIM;
  // gelu(tanh-approx) via sigmoid: 0.5v(1+tanh(z)) = v / (1 + exp2(-2*log2e*z))
  __syncthreads();                       // all waves done reading gemm LDS
  unsigned short* lout = (unsigned short*)lds;
  const int LST = 136;                   // row stride (ushorts)
#pragma unroll
  for (int ni = 0; ni < 2; ni++) {
    int lcol = wc * 32 + ni * 16 + lr;
    float bv = bias[n0 + lcol];
#pragma unroll
    for (int mi = 0; mi < 4; mi++) {
#pragma unroll
      for (int r = 0; r < 4; r++) {
        int lrow = wr * 64 + mi * 16 + q * 4 + r;
        float v = acc[mi][ni][r] + bv;
        float z = v * fmaf(0.0356774081f, v * v, 0.7978845608f);
        float ex = __builtin_amdgcn_exp2f(-2.8853900818f * z);
        float g = v * __builtin_amdgcn_rcpf(1.0f + ex);
        lout[lrow * LST + lcol] = f2b(g);
      }
    }
  }
  __syncthreads();
  // coalesced write-out: 2048 ushort8 chunks; wave covers 4 full 256B rows
#pragma unroll
  for (int p = 0; p < 4; p++) {
    int idx = p * 512 + tid;
    int row = idx >> 4, c8 = idx & 15;
    ushort8 v = *(const ushort8*)(lout + row * LST + c8 * 8);
    *(ushort8*)(h + (size_t)(row0 + row) * H_DIM + n0 + c8 * 8) = v;
  }
}

// ================= 256x256 tile, BK=64, 8-phase deep pipeline (FC2) =========
__device__ __forceinline__ void gemm8p(
    const char* __restrict__ Ab, size_t ldaB,
    const char* __restrict__ Bb, size_t ldbB, int ktiles,
    char* lds, int tid, f32x4 acc[8][4]) {
  const int w = tid >> 6, l = tid & 63;
  const int wr = w >> 2, wc = w & 3;
  const int lr = l & 15, kc = l >> 4;
  const int sw = (lr >> 1) & 7;
  const int s0 = ((kc ^ sw) << 4);         // kk=0 slot byte
  const int s1 = s0 ^ 64;                  // kk=1: chunk+4 == slot^4
  const int arow = ((wr << 7) + lr) << 7;            // A: row*128
  const int brow = 32768 + (((wc << 6) + lr) << 7);  // B region
  const int rl0 = tid >> 3;
  const int cg0 = (tid & 7) ^ ((rl0 >> 1) & 7);
  const size_t oA0 = (size_t)rl0 * ldaB + (cg0 << 4);
  const size_t oA1 = oA0 + (ldaB << 6);
  const size_t oB0 = (size_t)rl0 * ldbB + (cg0 << 4);
  const size_t oB1 = oB0 + (ldbB << 6);
  const int wb = w << 10;                  // wave-uniform LDS base (+lane*16)

#define SA(b, h, kt) do { \
    const char* s_ = Ab + (size_t)(h) * 128 * ldaB + (size_t)(kt) * 128; \
    gll(s_ + oA0, lds + (b) * 65536 + (h) * 16384 + wb); \
    gll(s_ + oA1, lds + (b) * 65536 + (h) * 16384 + 8192 + wb); } while (0)
#define SB(b, h, kt) do { \
    const char* s_ = Bb + (size_t)(h) * 128 * ldbB + (size_t)(kt) * 128; \
    gll(s_ + oB0, lds + (b) * 65536 + 32768 + (h) * 16384 + wb); \
    gll(s_ + oB1, lds + (b) * 65536 + 32768 + (h) * 16384 + 8192 + wb); } while (0)
#define BAR() asm volatile("s_barrier" ::: "memory")
#define RDA(B, mb) do { \
    for (int mi = 0; mi < 4; mi++) { \
      af[mi][0] = *(const short8*)(lds + (B) + arow + ((mb) + mi) * 2048 + s0); \
      af[mi][1] = *(const short8*)(lds + (B) + arow + ((mb) + mi) * 2048 + s1); } } while (0)
#define RDB(B, nb) do { \
    for (int ni = 0; ni < 2; ni++) { \
      bf[(nb) + ni][0] = *(const short8*)(lds + (B) + brow + ((nb) + ni) * 2048 + s0); \
      bf[(nb) + ni][1] = *(const short8*)(lds + (B) + brow + ((nb) + ni) * 2048 + s1); } } while (0)
#define MM(mb, nb) do { \
    __builtin_amdgcn_s_setprio(1); \
    for (int mi = 0; mi < 4; mi++) \
      for (int ni = 0; ni < 2; ni++) \
        for (int kk = 0; kk < 2; kk++) \
          acc[(mb) + mi][(nb) + ni] = __builtin_amdgcn_mfma_f32_16x16x32_bf16( \
              af[mi][kk], bf[(nb) + ni][kk], acc[(mb) + mi][(nb) + ni], 0, 0, 0); \
    __builtin_amdgcn_s_setprio(0); } while (0)

  short8 af[4][2], bf[4][2];
  // prologue: tile0 (4 halves) then B of tile1 -> first wait retires tile0
  SB(0, 0, 0); SB(0, 1, 0); SA(0, 0, 0); SA(0, 1, 0);
  SB(1, 0, 1); SB(1, 1, 1);
  asm volatile("s_waitcnt vmcnt(4)" ::: "memory");
  BAR();
  const int iters = ktiles >> 1;
#pragma unroll 1
  for (int i = 0; i < iters; i++) {
    const int t1 = 2 * i + 1, t2 = 2 * i + 2, t3 = 2 * i + 3;
    const bool nl = (i + 1 < iters);
    // ---- K-tile 2i from buf0 ----
    RDA(0, 0); RDB(0, 0);          // p0
    SA(1, 0, t1);
    BAR(); MM(0, 0); BAR();
    RDB(0, 2);                     // p1
    SA(1, 1, t1);
    BAR(); MM(0, 2); BAR();
    RDA(0, 4);                     // p2
    if (nl) SB(0, 0, t2);
    BAR(); MM(4, 2); BAR();
    if (nl) SB(0, 1, t2);          // p3
    BAR(); MM(4, 0);
    if (nl) asm volatile("s_waitcnt vmcnt(4)" ::: "memory");
    else    asm volatile("s_waitcnt vmcnt(0)" ::: "memory");
    BAR();                         // publishes buf1 (tile 2i+1)
    // ---- K-tile 2i+1 from buf1 ----
    RDA(65536, 0); RDB(65536, 0);  // p4
    if (nl) SA(0, 0, t2);
    BAR(); MM(0, 0); BAR();
    RDB(65536, 2);                 // p5
    if (nl) SA(0, 1, t2);
    BAR(); MM(0, 2); BAR();
    RDA(65536, 4);                 // p6
    if (nl) SB(1, 0, t3);
    BAR(); MM(4, 2); BAR();
    if (nl) SB(1, 1, t3);          // p7
    BAR(); MM(4, 0);
    if (nl) {
      asm volatile("s_waitcnt vmcnt(4)" ::: "memory");
      BAR();                       // publishes buf0 (tile 2i+2)
    }
  }
#undef SA
#undef SB
#undef BAR
#undef RDA
#undef RDB
#undef MM
}

// ---------------- FC2: part[pos] = w * (h @ w_proj^T + b_proj) --------------
// K=3072 single pass, grid 216 = 8 x 9 x 3 (one full CU round)
__global__ __launch_bounds__(512, 2) void fc2_kernel(
    const unsigned short* __restrict__ h, const unsigned short* __restrict__ wpjb,
    const float* __restrict__ bproj, const int* __restrict__ po,
    const float* __restrict__ perm_w, unsigned short* __restrict__ part) {
  __shared__ char lds[131072];
  int bid = blockIdx.x;
  int r8 = bid & 7, g8 = bid >> 3;     // g8: 0..26
  int col = g8 % 3;
  int Sp  = g8 / 3;                    // 0..8
  int y   = r8 * 9 + Sp;               // 0..71
  int row0 = y * 256;
  if (row0 >= po[NEXP]) return;
  int e = 0;
#pragma unroll
  for (int i = 1; i < NEXP; i++) if (row0 >= po[i]) e = i;
  int n0 = col * 256;
  int tid = threadIdx.x;
  f32x4 acc[8][4];
#pragma unroll
  for (int mi = 0; mi < 8; mi++)
#pragma unroll
    for (int ni = 0; ni < 4; ni++) acc[mi][ni] = (f32x4){0.f, 0.f, 0.f, 0.f};
  gemm8p((const char*)(h + (size_t)row0 * H_DIM), (size_t)H_DIM * 2,
         (const char*)(wpjb + (size_t)e * C_DIM * H_DIM + (size_t)n0 * H_DIM),
         (size_t)H_DIM * 2, H_DIM / 64, lds, tid, acc);
  int w = tid >> 6, l = tid & 63;
  int wr = w >> 2, wc = w & 3, lr = l & 15, q = l >> 4;
  const float* bias = bproj + (size_t)e * C_DIM;
#pragma unroll
  for (int mi = 0; mi < 8; mi++) {
#pragma unroll
    for (int r = 0; r < 4; r++) {
      int pos = row0 + wr * 128 + mi * 16 + q * 4 + r;
      float wgt = perm_w[pos];   // 0 for pad rows -> stores 0/junk, never read
#pragma unroll
      for (int ni = 0; ni < 4; ni++) {
        int colw = n0 + wc * 64 + ni * 16 + lr;
        float v = acc[mi][ni][r] + bias[colw];
        part[(size_t)pos * C_DIM + colw] = f2b(v * wgt);
      }
    }
  }
}

// ---------------- combine: out[t] = part[p0] + part[p1] ---------------------
__global__ __launch_bounds__(256) void combine_kernel(
    const unsigned short* __restrict__ part, const int* __restrict__ tok_pos,
    float* __restrict__ out) {
  const int NC4 = C_DIM / 4;                       // 192
  int idx = blockIdx.x * 256 + threadIdx.x;        // 0 .. N_TOK*192-1
  int t = idx / NC4, c4 = idx - t * NC4;
  int p0 = tok_pos[2 * t], p1 = tok_pos[2 * t + 1];
  ushort4 v0 = *(const ushort4*)(part + (size_t)p0 * C_DIM + c4 * 4);
  ushort4 v1 = *(const ushort4*)(part + (size_t)p1 * C_DIM + c4 * 4);
  float4 o;
  o.x = b2f(v0.x) + b2f(v1.x);
  o.y = b2f(v0.y) + b2f(v1.y);
  o.z = b2f(v0.z) + b2f(v1.z);
  o.w = b2f(v0.w) + b2f(v1.w);
  ((float4*)out)[idx] = o;
}

extern "C" void kernel_launch(void* const* d_in, const int* in_sizes, int n_in,
                              void* d_out, int out_size, void* d_ws, size_t ws_size,
                              hipStream_t stream) {
  const float* x     = (const float*)d_in[0];
  const float* gw    = (const float*)d_in[1];
  const float* gb    = (const float*)d_in[2];
  const float* wfc   = (const float*)d_in[3];
  const float* bfc   = (const float*)d_in[4];
  const float* wproj = (const float*)d_in[5];
  const float* bproj = (const float*)d_in[6];
  float* out = (float*)d_out;
  char* ws = (char*)d_ws;

  // ws layout (~179.7 MB, r4-identical): wpjb overlays wfcb (dead after fc1;
  // its wconv runs after fc1); part overlays xg (dead after fc1).
  int*   counts  = (int*)(ws + 0);
  int*   po      = (int*)(ws + 64);
  int*   tok_e   = (int*)(ws + 256);         // 2*8192 ints -> 65792
  int*   tok_r   = (int*)(ws + 65792);       //              -> 131328
  float* tok_w   = (float*)(ws + 131328);    //              -> 196864
  int*   tok_pos = (int*)(ws + 196864);      //              -> 262400
  float* perm_w  = (float*)(ws + 262400);    // 18432 f32    -> 336128
  unsigned short* wfcb = (unsigned short*)(ws + 409856);     // 8x3072x768 bf16 -> 38,158,592
  unsigned short* wpjb = (unsigned short*)(ws + 409856);     // overlay after fc1
  unsigned short* xg   = (unsigned short*)(ws + 38158592);   // 18432x768 bf16 -> 66,470,144
  unsigned short* part = (unsigned short*)(ws + 38158592);   // overlay after fc1
  unsigned short* hbuf = (unsigned short*)(ws + 66470144);   // 18432x3072 bf16 -> 179,716,352

  const int WN4 = NEXP * H_DIM * C_DIM / 4;

  hipMemsetAsync(counts, 0, 64, stream);
  gate_wconv_kernel<<<2048, 256, 0, stream>>>(x, gw, gb, wfc, counts,
                                              tok_e, tok_r, tok_w, perm_w, wfcb);
  scatgath_kernel<<<512, 256, 0, stream>>>(x, counts, tok_e, tok_r, tok_w,
                                           po, tok_pos, perm_w, xg);
  fc1_kernel<<<8 * 18 * 24, 512, 0, stream>>>(xg, wfcb, bfc, po, hbuf);
  wconv_kernel<<<2048, 256, 0, stream>>>(wproj, wpjb, WN4);
  fc2_kernel<<<8 * 9 * 3, 512, 0, stream>>>(hbuf, wpjb, bproj, po, perm_w, part);
  combine_kernel<<<N_TOK * (C_DIM / 4) / 256, 256, 0, stream>>>(part, tok_pos, out);
}